// Round 13
// baseline (473.342 us; speedup 1.0000x reference)
//
#include <hip/hip_runtime.h>
#include <float.h>

#define K_CODES 1024
#define DIM 64
#define T_LEN 8192
#define N_TOK 131072          // 16 * 8192 tokens
#define LO_SCALE 2048.0f

typedef _Float16 half8 __attribute__((ext_vector_type(8)));  // 4 VGPRs: MFMA A/B frag
typedef float    f32x4 __attribute__((ext_vector_type(4)));  // MFMA C/D frag

#define MFMA16(a, b, c) __builtin_amdgcn_mfma_f32_16x16x32_f16((a), (b), (c), 0, 0, 0)

// ---------------- prep: codebook -> tiled f16 hi/lo(x2048) + 2048*e_sq (r10) ----------------
__global__ void vq_prep(const float* __restrict__ cb,
                        _Float16* __restrict__ w,
                        float* __restrict__ wesq) {
    __shared__ float part[128];
    const int ct   = blockIdx.x;
    const int r    = threadIdx.x;
    const int halF = r >> 7;
    const int rr   = r & 127;
    const int q    = rr >> 4;
    const int code = rr & 15;

    const float* src = cb + (size_t)(ct * 16 + code) * DIM + q * 8;
    float4 v0 = *reinterpret_cast<const float4*>(src);
    float4 v1 = *reinterpret_cast<const float4*>(src + 4);
    float x[8] = {v0.x, v0.y, v0.z, v0.w, v1.x, v1.y, v1.z, v1.w};

    half8 o;
    float psum = 0.0f;
    #pragma unroll
    for (int j = 0; j < 8; ++j) {
        _Float16 h = (_Float16)x[j];
        o[j] = halF ? (_Float16)((x[j] - (float)h) * LO_SCALE) : h;  // exact residual
        psum = fmaf(x[j], x[j], psum);
    }
    *reinterpret_cast<half8*>(w + (size_t)ct * 2048 + halF * 1024 + q * 128 + code * 8) = o;

    if (halF == 0) part[rr] = psum;
    __syncthreads();
    if (r < 16) {
        float s = 0.0f;
        #pragma unroll
        for (int q2 = 0; q2 < 8; ++q2) s += part[q2 * 16 + r];
        wesq[ct * 16 + r] = s * LO_SCALE;   // pre-scaled: score' = 2048 * score
    }
}

// ---------------- main: r10 loop body, K-split across wave pairs (4 waves/SIMD) ----------------
// r6-r12: MFMA busy pinned ~21.5us inside 64-75us across B-path/ILP/shape/VALU variants.
// Last untested clean cell: r10's exact per-wave structure at HIGHER TLP. K-split:
// waves {0,1} scan codes 0..511 for the block's 2 strips, waves {2,3} codes 512..1023.
// Grid 1024 -> 4 waves/SIMD with r10's per-wave VALU:MFMA ratio (r8 confounded this by
// shrinking tokens/wave). Merge K-halves per token via LDS; tie -> half 0 (lower code).
__global__ __launch_bounds__(256, 4)
void vq_main(const float* __restrict__ in,
             const float* __restrict__ cb,
             const _Float16* __restrict__ w,
             const float* __restrict__ wesq,
             float* __restrict__ out) {
    __shared__ float esq_s[K_CODES];    // 4 KB (scaled x2048)
    __shared__ float kbest[2][128];
    __shared__ int   kidx[2][128];
    __shared__ int   idx_s[128];

    const int tid   = threadIdx.x;
    const int wave  = tid >> 6;
    const int lane  = tid & 63;
    const int lo4   = lane & 15;   // code residue (C col) / token residue (A m)
    const int quad  = lane >> 4;   // k-octet selector; token-row group in C
    const int sid   = wave & 1;    // strip id within block
    const int khalf = wave >> 1;   // codebook half: 0 -> codes 0..511, 1 -> 512..1023

    for (int k = tid; k < K_CODES; k += 256) esq_s[k] = wesq[k];
    __syncthreads();

    const int strip = blockIdx.x * 128 + sid * 64;   // 64 tokens per wave-pair strip
    const int b  = strip >> 13;
    const int t0 = strip & 8191;

    // ---- A fragments: -2x -> {ah, ah*2048 (exact), al*2048}; layout HW-verified r2-r12 ----
    const float* xin = in + (size_t)b * DIM * T_LEN + t0;
    half8 a_h[4][2], a_hs[4][2], a_l[4][2];
    #pragma unroll
    for (int mt = 0; mt < 4; ++mt) {
        #pragma unroll
        for (int s = 0; s < 2; ++s) {
            half8 hh, hs, ll;
            #pragma unroll
            for (int j = 0; j < 8; ++j) {
                const int d = s * 32 + quad * 8 + j;
                float xv = -2.0f * xin[(size_t)d * T_LEN + mt * 16 + lo4];
                _Float16 h = (_Float16)xv;
                hh[j] = h;
                hs[j] = (_Float16)((float)h * LO_SCALE);   // exact exponent shift
                ll[j] = (_Float16)((xv - (float)h) * LO_SCALE);
            }
            a_h[mt][s] = hh;
            a_hs[mt][s] = hs;
            a_l[mt][s] = ll;
        }
    }

    float best[16];
    int   bidx[16];
    #pragma unroll
    for (int i = 0; i < 16; ++i) { best[i] = FLT_MAX; bidx[i] = 0; }

    // this wave's 32 tiles start at tile khalf*32
    const _Float16* wb = w + (size_t)khalf * 32 * 2048 + (size_t)lane * 8;
    const int code0 = khalf * 512;

    half8 Ah0, Ah1, Al0, Al1, Bh0, Bh1, Bl0, Bl1;
    float Ae, Be;
    auto loadB = [&](int ct, half8& h0, half8& h1, half8& l0, half8& l1, float& es) {
        const _Float16* p = wb + (size_t)ct * 2048;
        h0 = *reinterpret_cast<const half8*>(p);          // hi, k 0..31
        h1 = *reinterpret_cast<const half8*>(p + 512);    // hi, k 32..63
        l0 = *reinterpret_cast<const half8*>(p + 1024);   // lo(x2048), k 0..31
        l1 = *reinterpret_cast<const half8*>(p + 1536);   // lo(x2048), k 32..63
        es = esq_s[code0 + ct * 16 + lo4];
    };
    auto step = [&](const half8& h0, const half8& h1, const half8& l0,
                    const half8& l1, float es, int ct) {
        const int code = code0 + ct * 16 + lo4;
        #pragma unroll
        for (int mt = 0; mt < 4; ++mt) {
            f32x4 c = {es, es, es, es};        // 2048*||e||^2
            c = MFMA16(a_hs[mt][0], h0, c);    // 2048*ah*bh
            c = MFMA16(a_hs[mt][1], h1, c);
            c = MFMA16(a_h[mt][0], l0, c);     // ah*(2048*bl)
            c = MFMA16(a_h[mt][1], l1, c);
            c = MFMA16(a_l[mt][0], h0, c);     // (2048*al)*bh
            c = MFMA16(a_l[mt][1], h1, c);
            #pragma unroll
            for (int r = 0; r < 4; ++r) {
                float sc = c[r];
                const int i = mt * 4 + r;
                bool lt = sc < best[i];         // strict <: first occurrence wins
                best[i] = lt ? sc : best[i];
                bidx[i] = lt ? code : bidx[i];
            }
        }
    };

    // ping-pong over this wave's 32 tiles
    loadB(0, Ah0, Ah1, Al0, Al1, Ae);
    loadB(1, Bh0, Bh1, Bl0, Bl1, Be);
    for (int p = 0; p < 15; ++p) {
        step(Ah0, Ah1, Al0, Al1, Ae, 2 * p);
        loadB(2 * p + 2, Ah0, Ah1, Al0, Al1, Ae);
        step(Bh0, Bh1, Bl0, Bl1, Be, 2 * p + 1);
        loadB(2 * p + 3, Bh0, Bh1, Bl0, Bl1, Be);
    }
    step(Ah0, Ah1, Al0, Al1, Ae, 30);
    step(Bh0, Bh1, Bl0, Bl1, Be, 31);

    // ---- cross-lane merge over the 16 code-residue lanes ----
    #pragma unroll
    for (int i = 0; i < 16; ++i) {
        float s = best[i];
        int  ix = bidx[i];
        #pragma unroll
        for (int off = 1; off < 16; off <<= 1) {
            float s2 = __shfl_xor(s, off, 64);
            int  ix2 = __shfl_xor(ix, off, 64);
            bool take = (s2 < s) || (s2 == s && ix2 < ix);  // tie -> lower index
            s  = take ? s2 : s;
            ix = take ? ix2 : ix;
        }
        if (lo4 == 0) {
            // token_local = mt*16 + quad*4 + r,  mt = i>>2, r = i&3
            const int tl = (i >> 2) * 16 + quad * 4 + (i & 3);
            kbest[khalf][sid * 64 + tl] = s;
            kidx [khalf][sid * 64 + tl] = ix;
        }
    }
    __syncthreads();

    // ---- combine the two K-halves per token (half 0 wins ties: lower code index) ----
    if (tid < 128) {
        float s0 = kbest[0][tid], s1 = kbest[1][tid];
        idx_s[tid] = (s1 < s0) ? kidx[1][tid] : kidx[0][tid];
    }
    __syncthreads();

    // ---- epilogue: 2 threads per token (32 dims each), gather + coalesced store ----
    const int tok_local = tid & 127;
    const int dhalf = tid >> 7;
    const int token = blockIdx.x * 128 + tok_local;
    const int tb = token >> 13;
    const int tt = token & 8191;
    const int my_idx = idx_s[tok_local];

    if (dhalf == 0)
        out[(size_t)N_TOK * DIM + token] = (float)my_idx;   // index output

    const float* crow = cb + (size_t)my_idx * DIM + dhalf * 32;
    float* outv = out + (size_t)tb * DIM * T_LEN + (size_t)(dhalf * 32) * T_LEN + tt;
    #pragma unroll
    for (int d0 = 0; d0 < 32; d0 += 4) {
        float4 v = *reinterpret_cast<const float4*>(crow + d0);  // L2-hot gather
        outv[(size_t)(d0 + 0) * T_LEN] = v.x;
        outv[(size_t)(d0 + 1) * T_LEN] = v.y;
        outv[(size_t)(d0 + 2) * T_LEN] = v.z;
        outv[(size_t)(d0 + 3) * T_LEN] = v.w;
    }
}

extern "C" void kernel_launch(void* const* d_in, const int* in_sizes, int n_in,
                              void* d_out, int out_size, void* d_ws, size_t ws_size,
                              hipStream_t stream) {
    const float* in = (const float*)d_in[0];   // (16, 64, 8192) fp32
    const float* cb = (const float*)d_in[1];   // (1024, 64) fp32
    float* out = (float*)d_out;

    _Float16* w   = (_Float16*)d_ws;                       // 64 tiles * 4 KB = 256 KB
    float*   wesq = (float*)((char*)d_ws + 64 * 4096);     // 4 KB

    vq_prep<<<dim3(64), dim3(256), 0, stream>>>(cb, w, wesq);
    vq_main<<<dim3(N_TOK / 128), dim3(256), 0, stream>>>(in, cb, w, wesq, out);
}

// Round 14
// 132.873 us; speedup vs baseline: 3.5624x; 3.5624x over previous
//
#include <hip/hip_runtime.h>
#include <float.h>

#define K_CODES 1024
#define DIM 64
#define T_LEN 8192
#define N_TOK 131072          // 16 * 8192 tokens
#define LO_SCALE 2048.0f

typedef _Float16 half8 __attribute__((ext_vector_type(8)));  // 4 VGPRs: MFMA A/B frag
typedef float    f32x4 __attribute__((ext_vector_type(4)));  // MFMA C/D frag

#define MFMA16(a, b, c) __builtin_amdgcn_mfma_f32_16x16x32_f16((a), (b), (c), 0, 0, 0)

// ---------------- prep: codebook -> tiled f16 hi/lo(x2048) + 2048*e_sq (r10) ----------------
__global__ void vq_prep(const float* __restrict__ cb,
                        _Float16* __restrict__ w,
                        float* __restrict__ wesq) {
    __shared__ float part[128];
    const int ct   = blockIdx.x;
    const int r    = threadIdx.x;
    const int halF = r >> 7;
    const int rr   = r & 127;
    const int q    = rr >> 4;
    const int code = rr & 15;

    const float* src = cb + (size_t)(ct * 16 + code) * DIM + q * 8;
    float4 v0 = *reinterpret_cast<const float4*>(src);
    float4 v1 = *reinterpret_cast<const float4*>(src + 4);
    float x[8] = {v0.x, v0.y, v0.z, v0.w, v1.x, v1.y, v1.z, v1.w};

    half8 o;
    float psum = 0.0f;
    #pragma unroll
    for (int j = 0; j < 8; ++j) {
        _Float16 h = (_Float16)x[j];
        o[j] = halF ? (_Float16)((x[j] - (float)h) * LO_SCALE) : h;  // exact residual
        psum = fmaf(x[j], x[j], psum);
    }
    *reinterpret_cast<half8*>(w + (size_t)ct * 2048 + halF * 1024 + q * 128 + code * 8) = o;

    if (halF == 0) part[rr] = psum;
    __syncthreads();
    if (r < 16) {
        float s = 0.0f;
        #pragma unroll
        for (int q2 = 0; q2 < 8; ++q2) s += part[q2 * 16 + r];
        wesq[ct * 16 + r] = s * LO_SCALE;   // pre-scaled: score' = 2048 * score
    }
}

// ---------------- main: r10 loop body, K-split across wave pairs ----------------
// r13 retry with launch_bounds(256,2): r13's (256,4) capped the allocator at 128 VGPR
// -> it buckled to 64 + 710 MB scratch (the 422us regression). With (256,2) the body
// compiles to ~104 VGPR (r10 codegen, no spill) and 104<=112 still PERMITS 4 waves/SIMD
// (m69: pool ~512/SIMD) — the TLP now comes from the grid: 1024 blocks = 4 blocks/CU.
// Waves {0,1}: codes 0..511 for the block's 2 strips; waves {2,3}: codes 512..1023.
__global__ __launch_bounds__(256, 2)
void vq_main(const float* __restrict__ in,
             const float* __restrict__ cb,
             const _Float16* __restrict__ w,
             const float* __restrict__ wesq,
             float* __restrict__ out) {
    __shared__ float esq_s[K_CODES];    // 4 KB (scaled x2048)
    __shared__ float kbest[2][128];
    __shared__ int   kidx[2][128];
    __shared__ int   idx_s[128];

    const int tid   = threadIdx.x;
    const int wave  = tid >> 6;
    const int lane  = tid & 63;
    const int lo4   = lane & 15;   // code residue (C col) / token residue (A m)
    const int quad  = lane >> 4;   // k-octet selector; token-row group in C
    const int sid   = wave & 1;    // strip id within block
    const int khalf = wave >> 1;   // codebook half: 0 -> codes 0..511, 1 -> 512..1023

    for (int k = tid; k < K_CODES; k += 256) esq_s[k] = wesq[k];
    __syncthreads();

    const int strip = blockIdx.x * 128 + sid * 64;   // 64 tokens per wave-pair strip
    const int b  = strip >> 13;
    const int t0 = strip & 8191;

    // ---- A fragments: -2x -> {ah, ah*2048 (exact), al*2048}; layout HW-verified r2-r13 ----
    const float* xin = in + (size_t)b * DIM * T_LEN + t0;
    half8 a_h[4][2], a_hs[4][2], a_l[4][2];
    #pragma unroll
    for (int mt = 0; mt < 4; ++mt) {
        #pragma unroll
        for (int s = 0; s < 2; ++s) {
            half8 hh, hs, ll;
            #pragma unroll
            for (int j = 0; j < 8; ++j) {
                const int d = s * 32 + quad * 8 + j;
                float xv = -2.0f * xin[(size_t)d * T_LEN + mt * 16 + lo4];
                _Float16 h = (_Float16)xv;
                hh[j] = h;
                hs[j] = (_Float16)((float)h * LO_SCALE);   // exact exponent shift
                ll[j] = (_Float16)((xv - (float)h) * LO_SCALE);
            }
            a_h[mt][s] = hh;
            a_hs[mt][s] = hs;
            a_l[mt][s] = ll;
        }
    }

    float best[16];
    int   bidx[16];
    #pragma unroll
    for (int i = 0; i < 16; ++i) { best[i] = FLT_MAX; bidx[i] = 0; }

    // this wave's 32 tiles start at tile khalf*32
    const _Float16* wb = w + (size_t)khalf * 32 * 2048 + (size_t)lane * 8;
    const int code0 = khalf * 512;

    half8 Ah0, Ah1, Al0, Al1, Bh0, Bh1, Bl0, Bl1;
    float Ae, Be;
    auto loadB = [&](int ct, half8& h0, half8& h1, half8& l0, half8& l1, float& es) {
        const _Float16* p = wb + (size_t)ct * 2048;
        h0 = *reinterpret_cast<const half8*>(p);          // hi, k 0..31
        h1 = *reinterpret_cast<const half8*>(p + 512);    // hi, k 32..63
        l0 = *reinterpret_cast<const half8*>(p + 1024);   // lo(x2048), k 0..31
        l1 = *reinterpret_cast<const half8*>(p + 1536);   // lo(x2048), k 32..63
        es = esq_s[code0 + ct * 16 + lo4];
    };
    auto step = [&](const half8& h0, const half8& h1, const half8& l0,
                    const half8& l1, float es, int ct) {
        const int code = code0 + ct * 16 + lo4;
        #pragma unroll
        for (int mt = 0; mt < 4; ++mt) {
            f32x4 c = {es, es, es, es};        // 2048*||e||^2
            c = MFMA16(a_hs[mt][0], h0, c);    // 2048*ah*bh
            c = MFMA16(a_hs[mt][1], h1, c);
            c = MFMA16(a_h[mt][0], l0, c);     // ah*(2048*bl)
            c = MFMA16(a_h[mt][1], l1, c);
            c = MFMA16(a_l[mt][0], h0, c);     // (2048*al)*bh
            c = MFMA16(a_l[mt][1], h1, c);
            #pragma unroll
            for (int r = 0; r < 4; ++r) {
                float sc = c[r];
                const int i = mt * 4 + r;
                bool lt = sc < best[i];         // strict <: first occurrence wins
                best[i] = lt ? sc : best[i];
                bidx[i] = lt ? code : bidx[i];
            }
        }
    };

    // ping-pong over this wave's 32 tiles
    loadB(0, Ah0, Ah1, Al0, Al1, Ae);
    loadB(1, Bh0, Bh1, Bl0, Bl1, Be);
    for (int p = 0; p < 15; ++p) {
        step(Ah0, Ah1, Al0, Al1, Ae, 2 * p);
        loadB(2 * p + 2, Ah0, Ah1, Al0, Al1, Ae);
        step(Bh0, Bh1, Bl0, Bl1, Be, 2 * p + 1);
        loadB(2 * p + 3, Bh0, Bh1, Bl0, Bl1, Be);
    }
    step(Ah0, Ah1, Al0, Al1, Ae, 30);
    step(Bh0, Bh1, Bl0, Bl1, Be, 31);

    // ---- cross-lane merge over the 16 code-residue lanes ----
    #pragma unroll
    for (int i = 0; i < 16; ++i) {
        float s = best[i];
        int  ix = bidx[i];
        #pragma unroll
        for (int off = 1; off < 16; off <<= 1) {
            float s2 = __shfl_xor(s, off, 64);
            int  ix2 = __shfl_xor(ix, off, 64);
            bool take = (s2 < s) || (s2 == s && ix2 < ix);  // tie -> lower index
            s  = take ? s2 : s;
            ix = take ? ix2 : ix;
        }
        if (lo4 == 0) {
            // token_local = mt*16 + quad*4 + r,  mt = i>>2, r = i&3
            const int tl = (i >> 2) * 16 + quad * 4 + (i & 3);
            kbest[khalf][sid * 64 + tl] = s;
            kidx [khalf][sid * 64 + tl] = ix;
        }
    }
    __syncthreads();

    // ---- combine the two K-halves per token (half 0 wins ties: lower code index) ----
    if (tid < 128) {
        float s0 = kbest[0][tid], s1 = kbest[1][tid];
        idx_s[tid] = (s1 < s0) ? kidx[1][tid] : kidx[0][tid];
    }
    __syncthreads();

    // ---- epilogue: 2 threads per token (32 dims each), gather + coalesced store ----
    const int tok_local = tid & 127;
    const int dhalf = tid >> 7;
    const int token = blockIdx.x * 128 + tok_local;
    const int tb = token >> 13;
    const int tt = token & 8191;
    const int my_idx = idx_s[tok_local];

    if (dhalf == 0)
        out[(size_t)N_TOK * DIM + token] = (float)my_idx;   // index output

    const float* crow = cb + (size_t)my_idx * DIM + dhalf * 32;
    float* outv = out + (size_t)tb * DIM * T_LEN + (size_t)(dhalf * 32) * T_LEN + tt;
    #pragma unroll
    for (int d0 = 0; d0 < 32; d0 += 4) {
        float4 v = *reinterpret_cast<const float4*>(crow + d0);  // L2-hot gather
        outv[(size_t)(d0 + 0) * T_LEN] = v.x;
        outv[(size_t)(d0 + 1) * T_LEN] = v.y;
        outv[(size_t)(d0 + 2) * T_LEN] = v.z;
        outv[(size_t)(d0 + 3) * T_LEN] = v.w;
    }
}

extern "C" void kernel_launch(void* const* d_in, const int* in_sizes, int n_in,
                              void* d_out, int out_size, void* d_ws, size_t ws_size,
                              hipStream_t stream) {
    const float* in = (const float*)d_in[0];   // (16, 64, 8192) fp32
    const float* cb = (const float*)d_in[1];   // (1024, 64) fp32
    float* out = (float*)d_out;

    _Float16* w   = (_Float16*)d_ws;                       // 64 tiles * 4 KB = 256 KB
    float*   wesq = (float*)((char*)d_ws + 64 * 4096);     // 4 KB

    vq_prep<<<dim3(64), dim3(256), 0, stream>>>(cb, w, wesq);
    vq_main<<<dim3(N_TOK / 128), dim3(256), 0, stream>>>(in, cb, w, wesq, out);
}

// Round 15
// 128.951 us; speedup vs baseline: 3.6707x; 1.0304x over previous
//
#include <hip/hip_runtime.h>
#include <float.h>

#define K_CODES 1024
#define DIM 64
#define T_LEN 8192
#define N_TOK 131072          // 16 * 8192 tokens
#define LO_SCALE 2048.0f

typedef _Float16 half8 __attribute__((ext_vector_type(8)));  // 4 VGPRs: MFMA A/B frag
typedef float    f32x4 __attribute__((ext_vector_type(4)));  // MFMA C/D frag

#define MFMA16(a, b, c) __builtin_amdgcn_mfma_f32_16x16x32_f16((a), (b), (c), 0, 0, 0)

// FINAL: exact round-10 kernel — the measured minimum of this family.
// r6-r14 elimination record (all: MFMA busy ~21.5us inside 64-75us):
//   B-path (global vs LDS), L2 pressure, occupancy (2->4 waves/SIMD, two ways),
//   ILP shape, VALU diet, MFMA shape (16x16 vs 32x32), fusion, K-split — all neutral
//   or regressions. r10 = 64.6us main / 128.2us total is the plateau.

// ---------------- prep: codebook -> tiled f16 hi/lo(x2048) + 2048*e_sq ----------------
// Tile ct (16 codes) = 4 KB contiguous: hi[q=0..7][code=0..15][j=0..7], lo(x2048) at +1024.
__global__ void vq_prep(const float* __restrict__ cb,
                        _Float16* __restrict__ w,
                        float* __restrict__ wesq) {
    __shared__ float part[128];
    const int ct   = blockIdx.x;
    const int r    = threadIdx.x;
    const int halF = r >> 7;
    const int rr   = r & 127;
    const int q    = rr >> 4;
    const int code = rr & 15;

    const float* src = cb + (size_t)(ct * 16 + code) * DIM + q * 8;
    float4 v0 = *reinterpret_cast<const float4*>(src);
    float4 v1 = *reinterpret_cast<const float4*>(src + 4);
    float x[8] = {v0.x, v0.y, v0.z, v0.w, v1.x, v1.y, v1.z, v1.w};

    half8 o;
    float psum = 0.0f;
    #pragma unroll
    for (int j = 0; j < 8; ++j) {
        _Float16 h = (_Float16)x[j];
        o[j] = halF ? (_Float16)((x[j] - (float)h) * LO_SCALE) : h;  // exact residual
        psum = fmaf(x[j], x[j], psum);
    }
    *reinterpret_cast<half8*>(w + (size_t)ct * 2048 + halF * 1024 + q * 128 + code * 8) = o;

    if (halF == 0) part[rr] = psum;
    __syncthreads();
    if (r < 16) {
        float s = 0.0f;
        #pragma unroll
        for (int q2 = 0; q2 < 8; ++q2) s += part[q2 * 16 + r];
        wesq[ct * 16 + r] = s * LO_SCALE;   // pre-scaled: score' = 2048 * score
    }
}

// ---------------- main: global-direct B + single-acc scaled score + 3-op argmin ----------------
// score' = 2048*||e||^2 + (2048 ah)bh + ah(2048 bl) + (2048 al)bh; argmin over score'
// equals argmin over score (monotone x2048). Same exact f16 product set as the
// ref-verified split => absmax 0. 64 tok/wave, ping-pong B prefetch, no loop barriers.
__global__ __launch_bounds__(256, 2)
void vq_main(const float* __restrict__ in,
             const float* __restrict__ cb,
             const _Float16* __restrict__ w,
             const float* __restrict__ wesq,
             float* __restrict__ out) {
    __shared__ float esq_s[K_CODES];   // 4 KB (scaled x2048)
    __shared__ int   idx_s[256];

    const int tid  = threadIdx.x;
    const int wave = tid >> 6;
    const int lane = tid & 63;
    const int lo4  = lane & 15;   // code residue (C col) / token residue (A m)
    const int quad = lane >> 4;   // k-octet selector; token-row group in C

    for (int k = tid; k < K_CODES; k += 256) esq_s[k] = wesq[k];
    __syncthreads();   // only barrier before the epilogue

    const int strip = blockIdx.x * 256 + wave * 64;   // 64 tokens per wave
    const int b  = strip >> 13;
    const int t0 = strip & 8191;

    // ---- A fragments: -2x -> ah (f16), ah_s = ah*2048 (exact), al = (x-ah)*2048 ----
    const float* xin = in + (size_t)b * DIM * T_LEN + t0;
    half8 a_h[4][2], a_hs[4][2], a_l[4][2];
    #pragma unroll
    for (int mt = 0; mt < 4; ++mt) {
        #pragma unroll
        for (int s = 0; s < 2; ++s) {
            half8 hh, hs, ll;
            #pragma unroll
            for (int j = 0; j < 8; ++j) {
                const int d = s * 32 + quad * 8 + j;
                float xv = -2.0f * xin[(size_t)d * T_LEN + mt * 16 + lo4];
                _Float16 h = (_Float16)xv;
                hh[j] = h;
                hs[j] = (_Float16)((float)h * LO_SCALE);            // exact exponent shift
                ll[j] = (_Float16)((xv - (float)h) * LO_SCALE);
            }
            a_h[mt][s] = hh;
            a_hs[mt][s] = hs;
            a_l[mt][s] = ll;
        }
    }

    float best[16];
    int   bidx[16];
    #pragma unroll
    for (int i = 0; i < 16; ++i) { best[i] = FLT_MAX; bidx[i] = 0; }

    // B frags (layout HW-verified r6-r14): tile base + lane*8, frags at +0/+512/+1024/+1536
    const _Float16* wb = w + (size_t)lane * 8;

    half8 Ah0, Ah1, Al0, Al1, Bh0, Bh1, Bl0, Bl1;
    float Ae, Be;
    auto loadB = [&](int ct, half8& h0, half8& h1, half8& l0, half8& l1, float& es) {
        const _Float16* p = wb + (size_t)ct * 2048;
        h0 = *reinterpret_cast<const half8*>(p);          // hi, k 0..31
        h1 = *reinterpret_cast<const half8*>(p + 512);    // hi, k 32..63
        l0 = *reinterpret_cast<const half8*>(p + 1024);   // lo(x2048), k 0..31
        l1 = *reinterpret_cast<const half8*>(p + 1536);   // lo(x2048), k 32..63
        es = esq_s[ct * 16 + lo4];
    };
    auto step = [&](const half8& h0, const half8& h1, const half8& l0,
                    const half8& l1, float es, int ct) {
        const int code = ct * 16 + lo4;
        #pragma unroll
        for (int mt = 0; mt < 4; ++mt) {
            f32x4 c = {es, es, es, es};        // 2048*||e||^2
            c = MFMA16(a_hs[mt][0], h0, c);    // 2048*ah*bh
            c = MFMA16(a_hs[mt][1], h1, c);
            c = MFMA16(a_h[mt][0], l0, c);     // ah*(2048*bl)
            c = MFMA16(a_h[mt][1], l1, c);
            c = MFMA16(a_l[mt][0], h0, c);     // (2048*al)*bh
            c = MFMA16(a_l[mt][1], h1, c);
            #pragma unroll
            for (int r = 0; r < 4; ++r) {
                float sc = c[r];                // scaled score, no fmaf needed
                const int i = mt * 4 + r;
                bool lt = sc < best[i];         // strict <: first occurrence wins
                best[i] = lt ? sc : best[i];
                bidx[i] = lt ? code : bidx[i];
            }
        }
    };

    // ping-pong: tile ct+1's 4 global loads in flight during tile ct's 24 MFMAs
    loadB(0, Ah0, Ah1, Al0, Al1, Ae);
    loadB(1, Bh0, Bh1, Bl0, Bl1, Be);
    for (int p = 0; p < 31; ++p) {
        step(Ah0, Ah1, Al0, Al1, Ae, 2 * p);
        loadB(2 * p + 2, Ah0, Ah1, Al0, Al1, Ae);
        step(Bh0, Bh1, Bl0, Bl1, Be, 2 * p + 1);
        loadB(2 * p + 3, Bh0, Bh1, Bl0, Bl1, Be);
    }
    step(Ah0, Ah1, Al0, Al1, Ae, 62);
    step(Bh0, Bh1, Bl0, Bl1, Be, 63);

    // ---- cross-lane merge over the 16 code-residue lanes ----
    #pragma unroll
    for (int i = 0; i < 16; ++i) {
        float s = best[i];
        int  ix = bidx[i];
        #pragma unroll
        for (int off = 1; off < 16; off <<= 1) {
            float s2 = __shfl_xor(s, off, 64);
            int  ix2 = __shfl_xor(ix, off, 64);
            bool take = (s2 < s) || (s2 == s && ix2 < ix);  // tie -> lower index
            s  = take ? s2 : s;
            ix = take ? ix2 : ix;
        }
        if (lo4 == 0) {
            // token_local = mt*16 + quad*4 + r,  mt = i>>2, r = i&3
            idx_s[wave * 64 + (i >> 2) * 16 + quad * 4 + (i & 3)] = ix;
        }
    }
    __syncthreads();

    // ---- epilogue: 1 thread per token, gather exact fp32 row + coalesced stores ----
    const int token = blockIdx.x * 256 + tid;
    const int tb = token >> 13;
    const int tt = token & 8191;
    const int my_idx = idx_s[tid];

    out[(size_t)N_TOK * DIM + token] = (float)my_idx;   // index output

    const float* crow = cb + (size_t)my_idx * DIM;
    float* outv = out + (size_t)tb * DIM * T_LEN + tt;
    #pragma unroll
    for (int d0 = 0; d0 < DIM; d0 += 4) {
        float4 v = *reinterpret_cast<const float4*>(crow + d0);  // L2-hot gather
        outv[(size_t)(d0 + 0) * T_LEN] = v.x;
        outv[(size_t)(d0 + 1) * T_LEN] = v.y;
        outv[(size_t)(d0 + 2) * T_LEN] = v.z;
        outv[(size_t)(d0 + 3) * T_LEN] = v.w;
    }
}

extern "C" void kernel_launch(void* const* d_in, const int* in_sizes, int n_in,
                              void* d_out, int out_size, void* d_ws, size_t ws_size,
                              hipStream_t stream) {
    const float* in = (const float*)d_in[0];   // (16, 64, 8192) fp32
    const float* cb = (const float*)d_in[1];   // (1024, 64) fp32
    float* out = (float*)d_out;

    _Float16* w   = (_Float16*)d_ws;                       // 64 tiles * 4 KB = 256 KB
    float*   wesq = (float*)((char*)d_ws + 64 * 4096);     // 4 KB

    vq_prep<<<dim3(64), dim3(256), 0, stream>>>(cb, w, wesq);
    vq_main<<<dim3(N_TOK / 256), dim3(256), 0, stream>>>(in, cb, w, wesq, out);
}